// Round 1
// baseline (1270.389 us; speedup 1.0000x reference)
//
#include <hip/hip_runtime.h>

#define TT 2048
#define BB 16
#define DD 1024
#define BD (BB * DD)   // 16384

// ---------------------------------------------------------------------------
// GEMM: C[m,e] = sum_k A[m,k] * W[e,k]   (A row-major [M,1024], W row-major
// [1024,1024], C row-major [M,1024]). fp32 vector-ALU, 128x128 block tile,
// TK=8, 256 threads, 8x8 micro-tile per thread.
// ---------------------------------------------------------------------------
__global__ __launch_bounds__(256) void gemm_f32(const float* __restrict__ A,
                                                const float* __restrict__ W,
                                                float* __restrict__ C) {
    __shared__ float As[8][128];   // [k][m] transposed for vector LDS reads
    __shared__ float Ws[8][128];   // [k][n]

    const int tid = threadIdx.x;
    const int bm = blockIdx.x * 128;
    const int bn = blockIdx.y * 128;

    // staging: each thread loads one float4 of A and one of W per k-tile
    const int lm = tid >> 1;          // 0..127 (row within tile)
    const int lk = (tid & 1) << 2;    // 0 or 4 (k offset)
    const float* Ap = A + (size_t)(bm + lm) * DD + lk;
    const float* Wp = W + (size_t)(bn + lm) * DD + lk;

    const int tx = tid & 15;          // n-dir, 16 threads
    const int ty = tid >> 4;          // m-dir, 16 threads

    float acc[8][8];
#pragma unroll
    for (int i = 0; i < 8; ++i)
#pragma unroll
        for (int j = 0; j < 8; ++j) acc[i][j] = 0.f;

    for (int k0 = 0; k0 < DD; k0 += 8) {
        const float4 av = *(const float4*)(Ap + k0);
        const float4 wv = *(const float4*)(Wp + k0);
        __syncthreads();   // previous iteration's compute must be done
        As[lk + 0][lm] = av.x; As[lk + 1][lm] = av.y;
        As[lk + 2][lm] = av.z; As[lk + 3][lm] = av.w;
        Ws[lk + 0][lm] = wv.x; Ws[lk + 1][lm] = wv.y;
        Ws[lk + 2][lm] = wv.z; Ws[lk + 3][lm] = wv.w;
        __syncthreads();
#pragma unroll
        for (int k = 0; k < 8; ++k) {
            float a[8], w[8];
            *(float4*)&a[0] = *(const float4*)&As[k][ty * 8];
            *(float4*)&a[4] = *(const float4*)&As[k][ty * 8 + 4];
            *(float4*)&w[0] = *(const float4*)&Ws[k][tx * 8];
            *(float4*)&w[4] = *(const float4*)&Ws[k][tx * 8 + 4];
#pragma unroll
            for (int i = 0; i < 8; ++i)
#pragma unroll
                for (int j = 0; j < 8; ++j)
                    acc[i][j] = fmaf(a[i], w[j], acc[i][j]);
        }
    }

#pragma unroll
    for (int i = 0; i < 8; ++i) {
        float* cp = C + (size_t)(bm + ty * 8 + i) * DD + bn + tx * 8;
        float4 v0 = make_float4(acc[i][0], acc[i][1], acc[i][2], acc[i][3]);
        float4 v1 = make_float4(acc[i][4], acc[i][5], acc[i][6], acc[i][7]);
        *(float4*)cp       = v0;
        *(float4*)(cp + 4) = v1;
    }
}

// ---------------------------------------------------------------------------
// Scan: 16384 independent scalar recurrences (one per (b,e) lane).
//   h = tanh(xw[t] + bias + d_c * h);  out = h*h*sigmoid(h)
// Threads consecutive in e -> perfectly coalesced loads/stores each t.
// ---------------------------------------------------------------------------
__device__ __forceinline__ float fast_tanh(float x) {
    // tanh(x) = 1 - 2/(exp(2x)+1); clamp so exp never overflows (tanh(15)~1).
    x = fminf(fmaxf(x, -15.f), 15.f);
    float e = __expf(2.f * x);
    float r = __builtin_amdgcn_rcpf(e + 1.f);
    return fmaf(-2.f, r, 1.f);
}

__global__ __launch_bounds__(64) void scan_step(const float* __restrict__ xw,
                                                const float* __restrict__ dvec,
                                                const float* __restrict__ bvec,
                                                const float* __restrict__ h0,
                                                float* __restrict__ out,
                                                float* __restrict__ hout,
                                                int Tc, int first) {
    const int l = blockIdx.x * 64 + threadIdx.x;   // 0..BD-1
    const int e = l & (DD - 1);
    const float dc   = fminf(fmaxf(dvec[e], -0.99f), 0.99f);
    const float bias = bvec[e];

    float h;
    if (first) {
        h = h0[l];
        hout[l] = h;           // h[0] = h0
    } else {
        h = hout[l];           // state left by previous chunk
    }

    for (int t = 0; t < Tc; t += 8) {
        float v[8];
#pragma unroll
        for (int i = 0; i < 8; ++i)
            v[i] = xw[(size_t)(t + i) * BD + l];
#pragma unroll
        for (int i = 0; i < 8; ++i) {
            h = fast_tanh(v[i] + bias + dc * h);
            float s = __builtin_amdgcn_rcpf(1.f + __expf(-h));  // sigmoid(h)
            out[(size_t)(t + i) * BD + l]      = h * h * s;
            hout[(size_t)(t + i + 1) * BD + l] = h;
        }
    }
}

// ---------------------------------------------------------------------------
extern "C" void kernel_launch(void* const* d_in, const int* in_sizes, int n_in,
                              void* d_out, int out_size, void* d_ws, size_t ws_size,
                              hipStream_t stream) {
    const float* x  = (const float*)d_in[0];   // [T,B,D]
    const float* h0 = (const float*)d_in[1];   // [B,D]
    const float* Wx = (const float*)d_in[2];   // [D,D]
    const float* dv = (const float*)d_in[3];   // [D]
    const float* bv = (const float*)d_in[4];   // [D]

    float* out  = (float*)d_out;               // [T,B,D]
    float* hout = out + (size_t)TT * BD;       // [T+1,B,D]
    float* xw   = (float*)d_ws;                // scratch [Tc,B,D]

    // chunk T by workspace capacity; Tc multiple of 8 so M = Tc*16 % 128 == 0
    size_t maxTc = ws_size / ((size_t)BD * sizeof(float));
    long long Tc = (long long)((maxTc / 8) * 8);
    if (Tc > TT) Tc = TT;
    if (Tc < 8) Tc = 8;

    for (int t0 = 0; t0 < TT; ) {
        int tc = (int)Tc;
        if (tc > TT - t0) tc = TT - t0;
        const int M = tc * BB;
        dim3 grid(M / 128, DD / 128);
        gemm_f32<<<grid, 256, 0, stream>>>(x + (size_t)t0 * BD, Wx, xw);
        scan_step<<<BD / 64, 64, 0, stream>>>(xw, dv, bv, h0,
                                              out  + (size_t)t0 * BD,
                                              hout + (size_t)t0 * BD,
                                              tc, t0 == 0);
        t0 += tc;
    }
}

// Round 2
// 765.510 us; speedup vs baseline: 1.6595x; 1.6595x over previous
//
#include <hip/hip_runtime.h>

#define TT 2048
#define BB 16
#define DD 1024
#define BD (BB * DD)   // 16384

typedef _Float16 f16;
typedef _Float16 f16x8 __attribute__((ext_vector_type(8)));
typedef float f32x4 __attribute__((ext_vector_type(4)));
typedef unsigned int u32;

// async global->LDS, 16B per lane. LDS dest = wave-uniform base + lane*16.
__device__ __forceinline__ void gload_lds16(const void* g, const void* s) {
    const __attribute__((address_space(1))) u32* gp =
        (const __attribute__((address_space(1))) u32*)(unsigned long long)(size_t)g;
    __attribute__((address_space(3))) u32* sp =
        (__attribute__((address_space(3))) u32*)(u32)(size_t)s;
    __builtin_amdgcn_global_load_lds(gp, sp, 16, 0, 0);
}

// ---------------------------------------------------------------------------
// fp32 -> fp16 convert (8 elems/thread/iter, grid-stride)
// ---------------------------------------------------------------------------
__global__ __launch_bounds__(256) void cvt_f16(const float* __restrict__ in,
                                               f16* __restrict__ out, int n8) {
    int i = blockIdx.x * 256 + threadIdx.x;
    const int stride = gridDim.x * 256;
    for (; i < n8; i += stride) {
        const float4* p = (const float4*)in + (size_t)i * 2;
        float4 a = p[0], b = p[1];
        f16x8 o;
        o[0] = (f16)a.x; o[1] = (f16)a.y; o[2] = (f16)a.z; o[3] = (f16)a.w;
        o[4] = (f16)b.x; o[5] = (f16)b.y; o[6] = (f16)b.z; o[7] = (f16)b.w;
        *((f16x8*)out + i) = o;
    }
}

// ---------------------------------------------------------------------------
// MFMA GEMM: C[m,n] = sum_k A[m,k]*W[n,k], fp16 in / fp32 out.
// 128x128 block tile, BK=64, 256 threads = 4 waves (2x2), wave tile 64x64
// = 4x4 MFMA 16x16x32. LDS layout: row-major [128 rows][8 slots][8 f16],
// slot index XOR-swizzled by (row&7) to avoid bank conflicts on frag reads.
// ---------------------------------------------------------------------------
__global__ __launch_bounds__(256) void gemm_f16(const f16* __restrict__ A,
                                                const f16* __restrict__ W,
                                                float* __restrict__ C) {
    __shared__ f16 As[128 * 64];
    __shared__ f16 Bs[128 * 64];

    const int tid = threadIdx.x;
    const int bm = blockIdx.y * 128;
    const int bn = blockIdx.x * 128;

    // staging: chunk c = r*256+tid -> row = c>>3 (r*32 + tid>>3), slot = c&7.
    // stored slot s holds global k-chunk kb = s ^ (row&7); since rows step by
    // 32 per round, (row&7) and hence kb are round-invariant.
    const int sm = tid >> 3;            // base row 0..31
    const int ss = tid & 7;             // slot
    const int kb = ss ^ (sm & 7);       // global k-chunk fetched by this lane

    const f16* Ag = A + (size_t)(bm + sm) * DD + kb * 8;
    const f16* Bg = W + (size_t)(bn + sm) * DD + kb * 8;

    const int wave = tid >> 6;
    const int lane = tid & 63;
    const int wm = (wave & 1) * 64;
    const int wn = (wave >> 1) * 64;
    const int fr = lane & 15;
    const int quad = lane >> 4;

    f32x4 acc[4][4];
#pragma unroll
    for (int i = 0; i < 4; ++i)
#pragma unroll
        for (int j = 0; j < 4; ++j) acc[i][j] = (f32x4){0.f, 0.f, 0.f, 0.f};

    for (int kt = 0; kt < 16; ++kt) {
        const f16* Agk = Ag + kt * 64;
        const f16* Bgk = Bg + kt * 64;
        __syncthreads();   // all waves done reading previous tile
#pragma unroll
        for (int r = 0; r < 4; ++r) {
            gload_lds16(Agk + (size_t)r * 32 * DD, (const char*)As + (r * 256 + tid) * 16);
            gload_lds16(Bgk + (size_t)r * 32 * DD, (const char*)Bs + (r * 256 + tid) * 16);
        }
        __syncthreads();   // compiler drains vmcnt before s_barrier

#pragma unroll
        for (int ks = 0; ks < 2; ++ks) {
            f16x8 af[4], bf[4];
#pragma unroll
            for (int i = 0; i < 4; ++i) {
                const int row = wm + i * 16 + fr;
                const int slot = (ks * 4 + quad) ^ (row & 7);
                af[i] = *(const f16x8*)((const char*)As + row * 128 + slot * 16);
            }
#pragma unroll
            for (int j = 0; j < 4; ++j) {
                const int row = wn + j * 16 + fr;
                const int slot = (ks * 4 + quad) ^ (row & 7);
                bf[j] = *(const f16x8*)((const char*)Bs + row * 128 + slot * 16);
            }
#pragma unroll
            for (int i = 0; i < 4; ++i)
#pragma unroll
                for (int j = 0; j < 4; ++j)
                    acc[i][j] = __builtin_amdgcn_mfma_f32_16x16x32_f16(af[i], bf[j], acc[i][j], 0, 0, 0);
        }
    }

    // C/D layout: col = lane&15 (n), row = quad*4 + reg (m)
#pragma unroll
    for (int i = 0; i < 4; ++i) {
        const int gm = bm + wm + i * 16 + quad * 4;
#pragma unroll
        for (int j = 0; j < 4; ++j) {
            const int gn = bn + wn + j * 16 + fr;
            float* cp = C + (size_t)gm * DD + gn;
#pragma unroll
            for (int r = 0; r < 4; ++r)
                cp[(size_t)r * DD] = acc[i][j][r];
        }
    }
}

// ---------------------------------------------------------------------------
// Scan: 16384 independent recurrences; 32-deep double-buffered register
// prefetch to keep ~128B/thread of reads in flight (latency hiding).
// ---------------------------------------------------------------------------
__device__ __forceinline__ void cell(float vb, float dc, float& h, float& o) {
    const float a = fmaf(dc, h, vb);             // |a| <~ 8, exp safe
    const float E = __expf(2.f * a);
    h = fmaf(-2.f, __builtin_amdgcn_rcpf(E + 1.f), 1.f);   // tanh(a)
    const float s = __builtin_amdgcn_rcpf(1.f + __expf(-h)); // sigmoid(h)
    o = h * h * s;
}

__global__ __launch_bounds__(64) void scan_step(const float* __restrict__ xw,
                                                const float* __restrict__ dvec,
                                                const float* __restrict__ bvec,
                                                const float* __restrict__ h0,
                                                float* __restrict__ out,
                                                float* __restrict__ hout,
                                                int Tc, int first) {
    const int l = blockIdx.x * 64 + threadIdx.x;
    const int e = l & (DD - 1);
    const float dc   = fminf(fmaxf(dvec[e], -0.99f), 0.99f);
    const float bias = bvec[e];

    float h;
    if (first) {
        h = h0[l];
        hout[l] = h;
    } else {
        h = hout[l];
    }

    const float* xp = xw + l;
    float va[32], vb[32];
#pragma unroll
    for (int i = 0; i < 32; ++i) va[i] = xp[(size_t)i * BD] + bias;

    for (int t0 = 0; t0 < Tc; t0 += 64) {
#pragma unroll
        for (int i = 0; i < 32; ++i) vb[i] = xp[(size_t)(t0 + 32 + i) * BD] + bias;
#pragma unroll
        for (int i = 0; i < 32; ++i) {
            float o;
            cell(va[i], dc, h, o);
            out[(size_t)(t0 + i) * BD + l]      = o;
            hout[(size_t)(t0 + i + 1) * BD + l] = h;
        }
        if (t0 + 64 < Tc) {
#pragma unroll
            for (int i = 0; i < 32; ++i) va[i] = xp[(size_t)(t0 + 64 + i) * BD] + bias;
        }
#pragma unroll
        for (int i = 0; i < 32; ++i) {
            float o;
            cell(vb[i], dc, h, o);
            out[(size_t)(t0 + 32 + i) * BD + l]      = o;
            hout[(size_t)(t0 + 32 + i + 1) * BD + l] = h;
        }
    }
}

// ---------------------------------------------------------------------------
extern "C" void kernel_launch(void* const* d_in, const int* in_sizes, int n_in,
                              void* d_out, int out_size, void* d_ws, size_t ws_size,
                              hipStream_t stream) {
    const float* x  = (const float*)d_in[0];   // [T,B,D]
    const float* h0 = (const float*)d_in[1];   // [B,D]
    const float* Wx = (const float*)d_in[2];   // [D,D]
    const float* dv = (const float*)d_in[3];   // [D]
    const float* bv = (const float*)d_in[4];   // [D]

    float* out  = (float*)d_out;               // [T,B,D]
    float* hout = out + (size_t)TT * BD;       // [T+1,B,D]

    // ws layout: [W_f16 2MB][x_f16 Tc*BD*2][xw fp32 Tc*BD*4]
    f16* Wf = (f16*)d_ws;
    const size_t wbytes = (size_t)DD * DD * sizeof(f16);
    const size_t rem = (ws_size > wbytes) ? ws_size - wbytes : 0;
    long long Tc = (long long)(rem / ((size_t)BD * 6));
    Tc = (Tc / 64) * 64;
    if (Tc > TT) Tc = TT;
    if (Tc < 64) Tc = 64;

    f16*   xf = (f16*)((char*)d_ws + wbytes);
    float* xw = (float*)((char*)d_ws + wbytes + (size_t)Tc * BD * 2);

    cvt_f16<<<512, 256, 0, stream>>>(Wx, Wf, DD * DD / 8);

    for (int t0 = 0; t0 < TT; ) {
        int tc = (int)Tc;
        if (tc > TT - t0) tc = TT - t0;
        const int n8 = tc * BD / 8;
        cvt_f16<<<2048, 256, 0, stream>>>(x + (size_t)t0 * BD, xf, n8);
        dim3 grid(DD / 128, tc * BB / 128);
        gemm_f16<<<grid, 256, 0, stream>>>(xf, Wf, xw);
        scan_step<<<BD / 64, 64, 0, stream>>>(xw, dv, bv, h0,
                                              out  + (size_t)t0 * BD,
                                              hout + (size_t)t0 * BD,
                                              tc, t0 == 0);
        t0 += tc;
    }
}